// Round 11
// baseline (1410.549 us; speedup 1.0000x reference)
//
#include <hip/hip_runtime.h>
#include <hip/hip_bf16.h>

// ---------------------------------------------------------------------------
// Fused 3-layer GRU (B*N=16384 seqs, T=20, HS=128) for MI355X / gfx950.
// R11: layer-wavefront, 4-wave blocks. Block = 32 seqs, 256 threads:
//   wave 0..2 -> layer w at t=s-1-w (ALL 8 ctiles, 2 seq-tiles),
//   wave 3    -> embedding e(t=s).
// Grid 512 -> 2 blocks/CU via LDS (68 KB) = two independent barrier domains,
// 2 waves/SIMD with VGPR budget 256 (no spill; R10's forced 64-VGPR squeeze
// caused 300 MB scratch traffic and the 932 us regression).
// 23 phases, one barrier each. Layer recurrence is wave-local (h(t-1) is the
// wave's own prior write); barrier only covers l-1 -> l and emb handoffs.
// ---------------------------------------------------------------------------

typedef _Float16 half8 __attribute__((ext_vector_type(8)));
typedef _Float16 half4 __attribute__((ext_vector_type(4)));
typedef float floatx4 __attribute__((ext_vector_type(4)));

#define MFMA16(a, b, c) __builtin_amdgcn_mfma_f32_16x16x32_f16((a), (b), (c), 0, 0, 0)

static __device__ __forceinline__ float ldin(const void* p, long i, bool f32) {
    return f32 ? ((const float*)p)[i]
               : __bfloat162float(((const __hip_bfloat16*)p)[i]);
}

static __device__ __forceinline__ bool detect_f32(const void* peT, const void* x) {
    const __hip_bfloat16* a = (const __hip_bfloat16*)peT;
    const __hip_bfloat16* b = (const __hip_bfloat16*)x;
    bool weird = false;
    for (int i = 0; i < 20; i++) {
        float v = fabsf(__bfloat162float(a[i]));
        if (!(v == 0.0f || (v > 1e-8f && v < 1e8f))) weird = true;
    }
    for (int i = 0; i < 64; i++) {
        float v = fabsf(__bfloat162float(b[i]));
        if (!(v == 0.0f || (v > 1e-8f && v < 1e8f))) weird = true;
    }
    return weird;
}

static __device__ __forceinline__ float fsigm(float x) {
    x = fminf(fmaxf(x, -60.f), 60.f);
    float e = __builtin_amdgcn_exp2f(-1.442695041f * x);
    return __builtin_amdgcn_rcpf(1.0f + e);
}
static __device__ __forceinline__ float ftanh(float x) {
    x = fminf(fmaxf(x, -30.f), 30.f);
    float e = __builtin_amdgcn_exp2f(2.885390082f * x);  // exp(2x)
    return 1.0f - 2.0f * __builtin_amdgcn_rcpf(1.0f + e);
}

// ws fragment layout (each frag = 512 halfs = 64 lanes x 8): slot order
//   [0,288)   Whh   (3 layers x 96)   frag in layer: (ctile*3+g)*4+ks, ctile 0..7
//   [288,480) WihR  (2 layers x 96)   same formula
//   [480,528) Wih0  (48)              (ctile*3+g)*2+ks   (K=64)
//   [528,544) outW  (16)              otile*4+ks
__global__ __launch_bounds__(64) void prepack_kernel(
    const void* __restrict__ Whh,
    const void* __restrict__ WihR,
    const void* __restrict__ Wih0,
    const void* __restrict__ outW,
    const void* __restrict__ peT,
    const void* __restrict__ x,
    _Float16* __restrict__ ws)
{
    const bool f32 = detect_f32(peT, x);
    int fid  = blockIdx.x;
    int lane = threadIdx.x;
    int nlo = lane & 15, quad = lane >> 4;
    const void* src;
    long base;
    int row, k0, ldk;
    if (fid < 288) {
        int l = fid / 96, r = fid % 96;
        int ks = r & 3, q1 = r >> 2, g = q1 % 3, ctile = q1 / 3;
        row = g * 128 + ctile * 16 + nlo; k0 = ks * 32 + quad * 8; ldk = 128;
        src = Whh; base = (long)l * 384 * 128;
    } else if (fid < 480) {
        int f = fid - 288; int l = f / 96, r = f % 96;
        int ks = r & 3, q1 = r >> 2, g = q1 % 3, ctile = q1 / 3;
        row = g * 128 + ctile * 16 + nlo; k0 = ks * 32 + quad * 8; ldk = 128;
        src = WihR; base = (long)l * 384 * 128;
    } else if (fid < 528) {
        int r = fid - 480;
        int ks = r & 1, q1 = r >> 1, g = q1 % 3, ctile = q1 / 3;
        row = g * 128 + ctile * 16 + nlo; k0 = ks * 32 + quad * 8; ldk = 64;
        src = Wih0; base = 0;
    } else {
        int r = fid - 528; int ks = r & 3, ot = r >> 2;
        row = ot * 16 + nlo; k0 = ks * 32 + quad * 8; ldk = 128;
        src = outW; base = 0;
    }
    _Float16* d = ws + (long)fid * 512 + lane * 8;
#pragma unroll
    for (int j = 0; j < 8; j++)
        d[j] = (_Float16)ldin(src, base + (long)row * ldk + k0 + j, f32);
}

__global__ __launch_bounds__(256, 2) void rnn_fused(
    const void* __restrict__ x,
    const void* __restrict__ peA,
    const void* __restrict__ peT,
    const void* __restrict__ embW,
    const void* __restrict__ embB,
    const void* __restrict__ bih,
    const void* __restrict__ bhh,
    const void* __restrict__ outB,
    const _Float16* __restrict__ ws,
    float* __restrict__ out)
{
    // h per layer, double-buffered by t parity: [l][buf][seq][col+pad]
    __shared__ __align__(16) _Float16 hA[3][2][32][136];
    __shared__ __align__(16) _Float16 eA[2][32][72];
    __shared__ float emb0[64], emb1[64], embb[64];
    __shared__ float biasS[1536];   // [l][R,Z,Ni,Nh][128]

    const bool f32 = detect_f32(peT, x);

    const int tid  = threadIdx.x;
    const int w    = tid >> 6;
    const int lane = tid & 63;
    const int nlo  = lane & 15;     // D col = seq-within-tile
    const int quad = lane >> 4;
    const int qk   = quad * 8;
    const int m0   = blockIdx.x * 32;

    for (int i = tid; i < 3 * 2 * 32 * 136; i += 256)
        (&hA[0][0][0][0])[i] = (_Float16)0.f;
    if (tid < 64) {
        emb0[tid] = ldin(embW, tid * 2 + 0, f32);
        emb1[tid] = ldin(embW, tid * 2 + 1, f32);
        embb[tid] = ldin(embB, tid, f32);
    }
    for (int idx = tid; idx < 1536; idx += 256) {
        int l = idx >> 9, r = idx & 511, g = r >> 7, c = r & 127;
        float v;
        if      (g == 0) v = ldin(bih, l * 384 + c, f32)       + ldin(bhh, l * 384 + c, f32);
        else if (g == 1) v = ldin(bih, l * 384 + 128 + c, f32) + ldin(bhh, l * 384 + 128 + c, f32);
        else if (g == 2) v = ldin(bih, l * 384 + 256 + c, f32);
        else             v = ldin(bhh, l * 384 + 256 + c, f32);
        biasS[idx] = v;
    }
    __syncthreads();

#pragma unroll 1
    for (int s = 0; s < 23; s++) {
        if (w == 3) {
            // ---- embedding wave: e(t=s) -> eA[s&1] ----
            if (s < 20) {
                int seq  = lane & 31;
                int hfc  = lane >> 5;         // 0..1 -> cols [hfc*32, +32)
                float x0 = ldin(x, ((long)(m0 + seq) * 20 + s) * 2 + 0, f32);
                float x1 = ldin(x, ((long)(m0 + seq) * 20 + s) * 2 + 1, f32);
                float pe = ldin(peT, s, f32) + ldin(peA, (m0 + seq) & 7, f32);
                float xp0 = x0 + pe, xp1 = x1 + pe;
                _Float16* erow = &eA[s & 1][seq][hfc * 32];
                const int cb = hfc * 32;
#pragma unroll
                for (int j = 0; j < 32; j++) {
                    float e = fmaf(emb0[cb + j], xp0, fmaf(emb1[cb + j], xp1, embb[cb + j]));
                    erow[j] = (_Float16)fmaxf(e, 0.f);
                }
            }
        } else {
            // ---- layer wave: layer l = w at t = s-1-l, all 8 ctiles ----
            const int l = w;
            const int t = s - 1 - l;
            if (t >= 0 && t < 20) {
                const int p = (t + 1) & 1;  // h(t-1) buf (own writes, last phase)
                const int q = t & 1;        // h(t) write buf
                const int KGI = (l == 0) ? 2 : 4;
                const _Float16* inBase = (l == 0) ? &eA[t & 1][0][0]
                                                  : &hA[l - 1][t & 1][0][0];
                const int inStride = (l == 0) ? 72 : 136;

                // resident B-op fragments (2 seq-tiles)
                half8 Bh[2][4];
#pragma unroll
                for (int rt = 0; rt < 2; rt++)
#pragma unroll
                    for (int ks = 0; ks < 4; ks++)
                        Bh[rt][ks] = *(const half8*)&hA[l][p][rt * 16 + nlo][ks * 32 + qk];
                half8 Bi[2][4];
#pragma unroll
                for (int rt = 0; rt < 2; rt++)
#pragma unroll
                    for (int ks = 0; ks < 4; ks++)
                        if (ks < KGI)
                            Bi[rt][ks] = *(const half8*)(inBase +
                                         (rt * 16 + nlo) * inStride + ks * 32 + qk);

#pragma unroll
                for (int ct = 0; ct < 8; ct++) {
                    const int c4 = ct * 16 + quad * 4;  // lane's first h-col

                    floatx4 acc[4][2];                  // [R,Z,Ni,Nh][rt]
#pragma unroll
                    for (int g = 0; g < 4; g++) {
                        floatx4 b = *(const floatx4*)&biasS[(l * 4 + g) * 128 + c4];
#pragma unroll
                        for (int rt = 0; rt < 2; rt++) acc[g][rt] = b;
                    }
                    // gh: h(t-1) @ Whh^T
#pragma unroll
                    for (int g = 0; g < 3; g++) {
                        const int ai = (g == 2) ? 3 : g;
#pragma unroll
                        for (int ks = 0; ks < 4; ks++) {
                            half8 Wf = *(const half8*)(ws +
                                ((long)(l * 96 + (ct * 3 + g) * 4 + ks)) * 512 + lane * 8);
#pragma unroll
                            for (int rt = 0; rt < 2; rt++)
                                acc[ai][rt] = MFMA16(Wf, Bh[rt][ks], acc[ai][rt]);
                        }
                    }
                    // gi: input(t) @ Wih^T
#pragma unroll
                    for (int ks = 0; ks < 4; ks++) {
                        if (ks < KGI) {
#pragma unroll
                            for (int g = 0; g < 3; g++) {
                                long f = (l == 0) ? (long)(480 + (ct * 3 + g) * 2 + ks)
                                                  : (long)(288 + (l - 1) * 96 + (ct * 3 + g) * 4 + ks);
                                half8 Uf = *(const half8*)(ws + f * 512 + lane * 8);
#pragma unroll
                                for (int rt = 0; rt < 2; rt++)
                                    acc[g][rt] = MFMA16(Uf, Bi[rt][ks], acc[g][rt]);
                            }
                        }
                    }
                    // nonlinearity + f16 writeback (b64) to buf q
#pragma unroll
                    for (int rt = 0; rt < 2; rt++) {
                        half4 ho = *(const half4*)&hA[l][p][rt * 16 + nlo][c4];
                        half4 hn;
#pragma unroll
                        for (int rg = 0; rg < 4; rg++) {
                            float r = fsigm(acc[0][rt][rg]);
                            float z = fsigm(acc[1][rt][rg]);
                            float n = ftanh(acc[2][rt][rg] + r * acc[3][rt][rg]);
                            hn[rg] = (_Float16)(n + z * ((float)ho[rg] - n));
                        }
                        *(half4*)&hA[l][q][rt * 16 + nlo][c4] = hn;
                    }
                }
            }
        }
        __syncthreads();   // single barrier per phase
    }

    // ---- epilogue 1: out = h3(19) @ outW^T + out_b ; h3(19) in buf 1 ----
    {
        const int otile = w;
        half8 Ao[4];
#pragma unroll
        for (int ks = 0; ks < 4; ks++)
            Ao[ks] = *(const half8*)(ws + ((long)(528 + otile * 4 + ks)) * 512 + lane * 8);
        floatx4 ob;
#pragma unroll
        for (int rg = 0; rg < 4; rg++) ob[rg] = ldin(outB, otile * 16 + quad * 4 + rg, f32);
#pragma unroll
        for (int st = 0; st < 2; st++) {
            floatx4 acc = ob;
#pragma unroll
            for (int ks = 0; ks < 4; ks++) {
                half8 b = *(const half8*)&hA[2][1][st * 16 + nlo][ks * 32 + qk];
                acc = MFMA16(Ao[ks], b, acc);
            }
            *(floatx4*)&out[(long)(m0 + st * 16 + nlo) * 64 + otile * 16 + quad * 4] = acc;
        }
    }

    // ---- epilogue 2: hidden finals (seq % 8 == 7), h_l(19) in buf 1 ----
    for (int idx = tid; idx < 3 * 4 * 128; idx += 256) {
        int l = idx >> 9, r = idx & 511, si = r >> 7, k = r & 127;
        int sq = si * 8 + 7;
        long m = m0 + sq;
        out[1048576L + ((long)l * 2048 + (m >> 3)) * 128 + k] =
            (float)hA[l][1][sq][k];
    }
}

extern "C" void kernel_launch(void* const* d_in, const int* in_sizes, int n_in,
                              void* d_out, int out_size, void* d_ws, size_t ws_size,
                              hipStream_t stream)
{
    int ix = 0, ipeA = 1, ipeT = 2, iembW = 3, iembB = 4, iWih0 = 5, iWihR = 6,
        iWhh = 7, ibih = 8, ibhh = 9, ioutW = 10, ioutB = 11;
    int f64 = -1, s64 = -1, f1152 = -1, s1152 = -1;
    for (int i = 0; i < n_in; i++) {
        int s = in_sizes[i];
        if      (s == 655360) ix = i;
        else if (s == 8)      ipeA = i;
        else if (s == 20)     ipeT = i;
        else if (s == 128)    iembW = i;
        else if (s == 24576)  iWih0 = i;
        else if (s == 98304)  iWihR = i;
        else if (s == 147456) iWhh = i;
        else if (s == 8192)   ioutW = i;
        else if (s == 64)     { if (f64 < 0) f64 = i; else s64 = i; }
        else if (s == 1152)   { if (f1152 < 0) f1152 = i; else s1152 = i; }
    }
    if (f64 >= 0)   { iembB = f64;  ioutB = (s64  >= 0 ? s64  : f64); }
    if (f1152 >= 0) { ibih = f1152; ibhh = (s1152 >= 0 ? s1152 : f1152); }

    _Float16* ws = (_Float16*)d_ws;           // 544 frags * 1KB = 557056 B
    float* out = (float*)d_out;

    hipLaunchKernelGGL(prepack_kernel, dim3(544), dim3(64), 0, stream,
                       d_in[iWhh], d_in[iWihR], d_in[iWih0], d_in[ioutW],
                       d_in[ipeT], d_in[ix], ws);
    hipLaunchKernelGGL(rnn_fused, dim3(512), dim3(256), 0, stream,
                       d_in[ix], d_in[ipeA], d_in[ipeT], d_in[iembW], d_in[iembB],
                       d_in[ibih], d_in[ibhh], d_in[ioutB], ws, out);
}

// Round 12
// 496.192 us; speedup vs baseline: 2.8427x; 2.8427x over previous
//
#include <hip/hip_runtime.h>
#include <hip/hip_bf16.h>

// ---------------------------------------------------------------------------
// Fused 3-layer GRU (B*N=16384 seqs, T=20, HS=128) for MI355X / gfx950.
// R12: R9's layer-wavefront (64 seqs/block, grid 256 = 1 block/CU, 23 phases,
// one barrier each) with the per-layer work split across 4 waves (2 ctiles
// each) instead of 2 (4 ctiles): per-wave sequential path halves. 12 waves =
// 768 threads, 3 waves/SIMD. Embedding is fused into layer-0 waves (computed
// after their GRU step, published by the same barrier; eA double-buffered).
// R11 lesson: >2 ctiles/wave at reduced VGPR budget spills (FETCH 834 MB);
// this keeps R9's register envelope per wave. launch_bounds(768,3) ~170 VGPR.
// ---------------------------------------------------------------------------

typedef _Float16 half8 __attribute__((ext_vector_type(8)));
typedef _Float16 half4 __attribute__((ext_vector_type(4)));
typedef float floatx4 __attribute__((ext_vector_type(4)));

#define MFMA16(a, b, c) __builtin_amdgcn_mfma_f32_16x16x32_f16((a), (b), (c), 0, 0, 0)

static __device__ __forceinline__ float ldin(const void* p, long i, bool f32) {
    return f32 ? ((const float*)p)[i]
               : __bfloat162float(((const __hip_bfloat16*)p)[i]);
}

static __device__ __forceinline__ bool detect_f32(const void* peT, const void* x) {
    const __hip_bfloat16* a = (const __hip_bfloat16*)peT;
    const __hip_bfloat16* b = (const __hip_bfloat16*)x;
    bool weird = false;
    for (int i = 0; i < 20; i++) {
        float v = fabsf(__bfloat162float(a[i]));
        if (!(v == 0.0f || (v > 1e-8f && v < 1e8f))) weird = true;
    }
    for (int i = 0; i < 64; i++) {
        float v = fabsf(__bfloat162float(b[i]));
        if (!(v == 0.0f || (v > 1e-8f && v < 1e8f))) weird = true;
    }
    return weird;
}

static __device__ __forceinline__ float fsigm(float x) {
    x = fminf(fmaxf(x, -60.f), 60.f);
    float e = __builtin_amdgcn_exp2f(-1.442695041f * x);
    return __builtin_amdgcn_rcpf(1.0f + e);
}
static __device__ __forceinline__ float ftanh(float x) {
    x = fminf(fmaxf(x, -30.f), 30.f);
    float e = __builtin_amdgcn_exp2f(2.885390082f * x);  // exp(2x)
    return 1.0f - 2.0f * __builtin_amdgcn_rcpf(1.0f + e);
}

// ws fragment layout (each frag = 512 halfs = 64 lanes x 8): slot order
//   [0,288)   Whh   (3 layers x 96)   frag in layer: (ctile*3+g)*4+ks, ctile 0..7
//   [288,480) WihR  (2 layers x 96)   same formula
//   [480,528) Wih0  (48)              (ctile*3+g)*2+ks   (K=64)
//   [528,544) outW  (16)              otile*4+ks
__global__ __launch_bounds__(64) void prepack_kernel(
    const void* __restrict__ Whh,
    const void* __restrict__ WihR,
    const void* __restrict__ Wih0,
    const void* __restrict__ outW,
    const void* __restrict__ peT,
    const void* __restrict__ x,
    _Float16* __restrict__ ws)
{
    const bool f32 = detect_f32(peT, x);
    int fid  = blockIdx.x;
    int lane = threadIdx.x;
    int nlo = lane & 15, quad = lane >> 4;
    const void* src;
    long base;
    int row, k0, ldk;
    if (fid < 288) {
        int l = fid / 96, r = fid % 96;
        int ks = r & 3, q1 = r >> 2, g = q1 % 3, ctile = q1 / 3;
        row = g * 128 + ctile * 16 + nlo; k0 = ks * 32 + quad * 8; ldk = 128;
        src = Whh; base = (long)l * 384 * 128;
    } else if (fid < 480) {
        int f = fid - 288; int l = f / 96, r = f % 96;
        int ks = r & 3, q1 = r >> 2, g = q1 % 3, ctile = q1 / 3;
        row = g * 128 + ctile * 16 + nlo; k0 = ks * 32 + quad * 8; ldk = 128;
        src = WihR; base = (long)l * 384 * 128;
    } else if (fid < 528) {
        int r = fid - 480;
        int ks = r & 1, q1 = r >> 1, g = q1 % 3, ctile = q1 / 3;
        row = g * 128 + ctile * 16 + nlo; k0 = ks * 32 + quad * 8; ldk = 64;
        src = Wih0; base = 0;
    } else {
        int r = fid - 528; int ks = r & 3, ot = r >> 2;
        row = ot * 16 + nlo; k0 = ks * 32 + quad * 8; ldk = 128;
        src = outW; base = 0;
    }
    _Float16* d = ws + (long)fid * 512 + lane * 8;
#pragma unroll
    for (int j = 0; j < 8; j++)
        d[j] = (_Float16)ldin(src, base + (long)row * ldk + k0 + j, f32);
}

__global__ __launch_bounds__(768, 3) void rnn_fused(
    const void* __restrict__ x,
    const void* __restrict__ peA,
    const void* __restrict__ peT,
    const void* __restrict__ embW,
    const void* __restrict__ embB,
    const void* __restrict__ bih,
    const void* __restrict__ bhh,
    const void* __restrict__ outB,
    const _Float16* __restrict__ ws,
    float* __restrict__ out)
{
    // h per layer, double-buffered by t parity: [l][buf][seq][col+pad]
    __shared__ __align__(16) _Float16 hA[3][2][64][136];
    __shared__ __align__(16) _Float16 eA[2][64][72];
    __shared__ float emb0[64], emb1[64], embb[64];
    __shared__ float biasS[1536];   // [l][R,Z,Ni,Nh][128]

    const bool f32 = detect_f32(peT, x);

    const int tid  = threadIdx.x;
    const int w    = tid >> 6;      // 0..11
    const int lane = tid & 63;
    const int nlo  = lane & 15;     // D col = seq-within-tile
    const int quad = lane >> 4;
    const int qk   = quad * 8;
    const int m0   = blockIdx.x * 64;

    for (int i = tid; i < 3 * 2 * 64 * 136; i += 768)
        (&hA[0][0][0][0])[i] = (_Float16)0.f;
    if (tid < 64) {
        emb0[tid] = ldin(embW, tid * 2 + 0, f32);
        emb1[tid] = ldin(embW, tid * 2 + 1, f32);
        embb[tid] = ldin(embB, tid, f32);
    }
    for (int idx = tid; idx < 1536; idx += 768) {
        int l = idx >> 9, r = idx & 511, g = r >> 7, c = r & 127;
        float v;
        if      (g == 0) v = ldin(bih, l * 384 + c, f32)       + ldin(bhh, l * 384 + c, f32);
        else if (g == 1) v = ldin(bih, l * 384 + 128 + c, f32) + ldin(bhh, l * 384 + 128 + c, f32);
        else if (g == 2) v = ldin(bih, l * 384 + 256 + c, f32);
        else             v = ldin(bhh, l * 384 + 256 + c, f32);
        biasS[idx] = v;
    }

    const int em = tid >> 2;          // embedding seq (layer-0 waves: tid<256)
    const int ej = (tid & 3) * 16;    // embedding col base
    const float peAg = ldin(peA, ((m0 + em) & 7), f32);

    __syncthreads();

#pragma unroll 1
    for (int s = 0; s < 23; s++) {
        const int l = w >> 2;           // 0..2
        const int W = w & 3;            // quarter: ctiles W*2, W*2+1
        const int t = s - 1 - l;
        if (t >= 0 && t < 20) {
            const int p = (t + 1) & 1;  // h(t-1) buf
            const int q = t & 1;        // h(t) write buf
            const int KGI = (l == 0) ? 2 : 4;
            const _Float16* inBase = (l == 0) ? &eA[t & 1][0][0]
                                              : &hA[l - 1][t & 1][0][0];
            const int inStride = (l == 0) ? 72 : 136;

            // resident B-op h fragments (full K=128, all 4 seq-tiles)
            half8 Bh[4][4];
#pragma unroll
            for (int rt = 0; rt < 4; rt++)
#pragma unroll
                for (int ks = 0; ks < 4; ks++)
                    Bh[rt][ks] = *(const half8*)&hA[l][p][rt * 16 + nlo][ks * 32 + qk];

#pragma unroll
            for (int ct = 0; ct < 2; ct++) {
                const int c8 = W * 2 + ct;          // ctile 0..7
                const int c4 = c8 * 16 + quad * 4;  // lane's first h-col

                floatx4 acc[4][4];                  // [R,Z,Ni,Nh][rt]
#pragma unroll
                for (int g = 0; g < 4; g++) {
                    floatx4 b = *(const floatx4*)&biasS[(l * 4 + g) * 128 + c4];
#pragma unroll
                    for (int rt = 0; rt < 4; rt++) acc[g][rt] = b;
                }
                // gh: h(t-1) @ Whh^T
#pragma unroll
                for (int g = 0; g < 3; g++) {
                    const int ai = (g == 2) ? 3 : g;
#pragma unroll
                    for (int ks = 0; ks < 4; ks++) {
                        half8 Wf = *(const half8*)(ws +
                            ((long)(l * 96 + (c8 * 3 + g) * 4 + ks)) * 512 + lane * 8);
#pragma unroll
                        for (int rt = 0; rt < 4; rt++)
                            acc[ai][rt] = MFMA16(Wf, Bh[rt][ks], acc[ai][rt]);
                    }
                }
                // gi: input(t) @ Wih^T   (Bi reloaded per ks -> low reg pressure)
                for (int ks = 0; ks < KGI; ks++) {
                    half8 Bi[4];
#pragma unroll
                    for (int rt = 0; rt < 4; rt++)
                        Bi[rt] = *(const half8*)(inBase +
                                 (rt * 16 + nlo) * inStride + ks * 32 + qk);
#pragma unroll
                    for (int g = 0; g < 3; g++) {
                        long f = (l == 0) ? (long)(480 + (c8 * 3 + g) * 2 + ks)
                                          : (long)(288 + (l - 1) * 96 + (c8 * 3 + g) * 4 + ks);
                        half8 Uf = *(const half8*)(ws + f * 512 + lane * 8);
#pragma unroll
                        for (int rt = 0; rt < 4; rt++)
                            acc[g][rt] = MFMA16(Uf, Bi[rt], acc[g][rt]);
                    }
                }
                // nonlinearity + f16 writeback (b64) to buf q
#pragma unroll
                for (int rt = 0; rt < 4; rt++) {
                    half4 ho = *(const half4*)&hA[l][p][rt * 16 + nlo][c4];
                    half4 hn;
#pragma unroll
                    for (int rg = 0; rg < 4; rg++) {
                        float r = fsigm(acc[0][rt][rg]);
                        float z = fsigm(acc[1][rt][rg]);
                        float n = ftanh(acc[2][rt][rg] + r * acc[3][rt][rg]);
                        hn[rg] = (_Float16)(n + z * ((float)ho[rg] - n));
                    }
                    *(half4*)&hA[l][q][rt * 16 + nlo][c4] = hn;
                }
            }
        }
        // ---- embedding fused into layer-0 waves: e(t=s) -> eA[s&1] ----
        if (l == 0 && s < 20) {
            float x0 = ldin(x, ((long)(m0 + em) * 20 + s) * 2 + 0, f32);
            float x1 = ldin(x, ((long)(m0 + em) * 20 + s) * 2 + 1, f32);
            float pe = ldin(peT, s, f32) + peAg;
            float xp0 = x0 + pe, xp1 = x1 + pe;
#pragma unroll
            for (int jj = 0; jj < 16; jj++) {
                float e = fmaf(emb0[ej + jj], xp0, fmaf(emb1[ej + jj], xp1, embb[ej + jj]));
                eA[s & 1][em][ej + jj] = (_Float16)fmaxf(e, 0.f);
            }
        }
        __syncthreads();   // single barrier per phase
    }

    // ---- epilogue 1: out = h3(19) @ outW^T + out_b ; h3(19) in buf 1 ----
    if (w < 8) {
        const int otile = w & 3;
        const int rtb   = (w >> 2) * 2;
        half8 Ao[4];
#pragma unroll
        for (int ks = 0; ks < 4; ks++)
            Ao[ks] = *(const half8*)(ws + ((long)(528 + otile * 4 + ks)) * 512 + lane * 8);
        floatx4 ob;
#pragma unroll
        for (int rg = 0; rg < 4; rg++) ob[rg] = ldin(outB, otile * 16 + quad * 4 + rg, f32);
#pragma unroll
        for (int rr = 0; rr < 2; rr++) {
            const int rt = rtb + rr;
            floatx4 acc = ob;
#pragma unroll
            for (int ks = 0; ks < 4; ks++) {
                half8 b = *(const half8*)&hA[2][1][rt * 16 + nlo][ks * 32 + qk];
                acc = MFMA16(Ao[ks], b, acc);
            }
            *(floatx4*)&out[(long)(m0 + rt * 16 + nlo) * 64 + otile * 16 + quad * 4] = acc;
        }
    }

    // ---- epilogue 2: hidden finals (seq % 8 == 7), h_l(19) in buf 1 ----
    for (int idx = tid; idx < 3 * 8 * 128; idx += 768) {
        int l2 = idx >> 10, r = idx & 1023, si = r >> 7, k = r & 127;
        int sq = si * 8 + 7;
        long m = m0 + sq;
        out[1048576L + ((long)l2 * 2048 + (m >> 3)) * 128 + k] =
            (float)hA[l2][1][sq][k];
    }
}

extern "C" void kernel_launch(void* const* d_in, const int* in_sizes, int n_in,
                              void* d_out, int out_size, void* d_ws, size_t ws_size,
                              hipStream_t stream)
{
    int ix = 0, ipeA = 1, ipeT = 2, iembW = 3, iembB = 4, iWih0 = 5, iWihR = 6,
        iWhh = 7, ibih = 8, ibhh = 9, ioutW = 10, ioutB = 11;
    int f64 = -1, s64 = -1, f1152 = -1, s1152 = -1;
    for (int i = 0; i < n_in; i++) {
        int s = in_sizes[i];
        if      (s == 655360) ix = i;
        else if (s == 8)      ipeA = i;
        else if (s == 20)     ipeT = i;
        else if (s == 128)    iembW = i;
        else if (s == 24576)  iWih0 = i;
        else if (s == 98304)  iWihR = i;
        else if (s == 147456) iWhh = i;
        else if (s == 8192)   ioutW = i;
        else if (s == 64)     { if (f64 < 0) f64 = i; else s64 = i; }
        else if (s == 1152)   { if (f1152 < 0) f1152 = i; else s1152 = i; }
    }
    if (f64 >= 0)   { iembB = f64;  ioutB = (s64  >= 0 ? s64  : f64); }
    if (f1152 >= 0) { ibih = f1152; ibhh = (s1152 >= 0 ? s1152 : f1152); }

    _Float16* ws = (_Float16*)d_ws;           // 544 frags * 1KB = 557056 B
    float* out = (float*)d_out;

    hipLaunchKernelGGL(prepack_kernel, dim3(544), dim3(64), 0, stream,
                       d_in[iWhh], d_in[iWihR], d_in[iWih0], d_in[ioutW],
                       d_in[ipeT], d_in[ix], ws);
    hipLaunchKernelGGL(rnn_fused, dim3(256), dim3(768), 0, stream,
                       d_in[ix], d_in[ipeA], d_in[ipeT], d_in[iembW], d_in[iembB],
                       d_in[ibih], d_in[ibhh], d_in[ioutB], ws, out);
}

// Round 13
// 383.571 us; speedup vs baseline: 3.6774x; 1.2936x over previous
//
#include <hip/hip_runtime.h>
#include <hip/hip_bf16.h>

// ---------------------------------------------------------------------------
// Fused 3-layer GRU (B*N=16384 seqs, T=20, HS=128) for MI355X / gfx950.
// R13 = R12 (layer-wavefront, 12 waves, 23 phases, 1 barrier each) with:
//  (a) per-block rotation of the weight-fragment walk (ks + ctile order) to
//      break the all-CUs-in-lockstep L2 slice hotspot (R6/R9/R12 invariant:
//      time tracks per-CU L2 weight volume at ~30 B/cyc -> slice contention);
//  (b) low-register-pressure inner loop (Bh per-ks scalars, acc[4][4] only
//      big live set) so no scratch spill at the 170-VGPR/3-wave budget
//      (R12: VGPR=84 + 372 MB FETCH = spill; canary: FETCH ~7.5 MB).
// ---------------------------------------------------------------------------

typedef _Float16 half8 __attribute__((ext_vector_type(8)));
typedef _Float16 half4 __attribute__((ext_vector_type(4)));
typedef float floatx4 __attribute__((ext_vector_type(4)));

#define MFMA16(a, b, c) __builtin_amdgcn_mfma_f32_16x16x32_f16((a), (b), (c), 0, 0, 0)

static __device__ __forceinline__ float ldin(const void* p, long i, bool f32) {
    return f32 ? ((const float*)p)[i]
               : __bfloat162float(((const __hip_bfloat16*)p)[i]);
}

static __device__ __forceinline__ bool detect_f32(const void* peT, const void* x) {
    const __hip_bfloat16* a = (const __hip_bfloat16*)peT;
    const __hip_bfloat16* b = (const __hip_bfloat16*)x;
    bool weird = false;
    for (int i = 0; i < 20; i++) {
        float v = fabsf(__bfloat162float(a[i]));
        if (!(v == 0.0f || (v > 1e-8f && v < 1e8f))) weird = true;
    }
    for (int i = 0; i < 64; i++) {
        float v = fabsf(__bfloat162float(b[i]));
        if (!(v == 0.0f || (v > 1e-8f && v < 1e8f))) weird = true;
    }
    return weird;
}

static __device__ __forceinline__ float fsigm(float x) {
    x = fminf(fmaxf(x, -60.f), 60.f);
    float e = __builtin_amdgcn_exp2f(-1.442695041f * x);
    return __builtin_amdgcn_rcpf(1.0f + e);
}
static __device__ __forceinline__ float ftanh(float x) {
    x = fminf(fmaxf(x, -30.f), 30.f);
    float e = __builtin_amdgcn_exp2f(2.885390082f * x);  // exp(2x)
    return 1.0f - 2.0f * __builtin_amdgcn_rcpf(1.0f + e);
}

// ws fragment layout (each frag = 512 halfs = 64 lanes x 8): slot order
//   [0,288)   Whh   (3 layers x 96)   frag in layer: (ctile*3+g)*4+ks, ctile 0..7
//   [288,480) WihR  (2 layers x 96)   same formula
//   [480,528) Wih0  (48)              (ctile*3+g)*2+ks   (K=64)
//   [528,544) outW  (16)              otile*4+ks
__global__ __launch_bounds__(64) void prepack_kernel(
    const void* __restrict__ Whh,
    const void* __restrict__ WihR,
    const void* __restrict__ Wih0,
    const void* __restrict__ outW,
    const void* __restrict__ peT,
    const void* __restrict__ x,
    _Float16* __restrict__ ws)
{
    const bool f32 = detect_f32(peT, x);
    int fid  = blockIdx.x;
    int lane = threadIdx.x;
    int nlo = lane & 15, quad = lane >> 4;
    const void* src;
    long base;
    int row, k0, ldk;
    if (fid < 288) {
        int l = fid / 96, r = fid % 96;
        int ks = r & 3, q1 = r >> 2, g = q1 % 3, ctile = q1 / 3;
        row = g * 128 + ctile * 16 + nlo; k0 = ks * 32 + quad * 8; ldk = 128;
        src = Whh; base = (long)l * 384 * 128;
    } else if (fid < 480) {
        int f = fid - 288; int l = f / 96, r = f % 96;
        int ks = r & 3, q1 = r >> 2, g = q1 % 3, ctile = q1 / 3;
        row = g * 128 + ctile * 16 + nlo; k0 = ks * 32 + quad * 8; ldk = 128;
        src = WihR; base = (long)l * 384 * 128;
    } else if (fid < 528) {
        int r = fid - 480;
        int ks = r & 1, q1 = r >> 1, g = q1 % 3, ctile = q1 / 3;
        row = g * 128 + ctile * 16 + nlo; k0 = ks * 32 + quad * 8; ldk = 64;
        src = Wih0; base = 0;
    } else {
        int r = fid - 528; int ks = r & 3, ot = r >> 2;
        row = ot * 16 + nlo; k0 = ks * 32 + quad * 8; ldk = 128;
        src = outW; base = 0;
    }
    _Float16* d = ws + (long)fid * 512 + lane * 8;
#pragma unroll
    for (int j = 0; j < 8; j++)
        d[j] = (_Float16)ldin(src, base + (long)row * ldk + k0 + j, f32);
}

__global__ __launch_bounds__(768, 3) void rnn_fused(
    const void* __restrict__ x,
    const void* __restrict__ peA,
    const void* __restrict__ peT,
    const void* __restrict__ embW,
    const void* __restrict__ embB,
    const void* __restrict__ bih,
    const void* __restrict__ bhh,
    const void* __restrict__ outB,
    const _Float16* __restrict__ ws,
    float* __restrict__ out)
{
    __shared__ __align__(16) _Float16 hA[3][2][64][136];
    __shared__ __align__(16) _Float16 eA[2][64][72];
    __shared__ float emb0[64], emb1[64], embb[64];
    __shared__ float biasS[1536];   // [l][R,Z,Ni,Nh][128]

    const bool f32 = detect_f32(peT, x);

    const int tid  = threadIdx.x;
    const int w    = tid >> 6;      // 0..11
    const int lane = tid & 63;
    const int nlo  = lane & 15;
    const int quad = lane >> 4;
    const int qk   = quad * 8;
    const int m0   = blockIdx.x * 64;
    const int rot  = blockIdx.x & 3;          // ks-order rotation (slice skew)
    const int ctr  = (blockIdx.x >> 2) & 1;   // ctile-order rotation

    for (int i = tid; i < 3 * 2 * 64 * 136; i += 768)
        (&hA[0][0][0][0])[i] = (_Float16)0.f;
    if (tid < 64) {
        emb0[tid] = ldin(embW, tid * 2 + 0, f32);
        emb1[tid] = ldin(embW, tid * 2 + 1, f32);
        embb[tid] = ldin(embB, tid, f32);
    }
    for (int idx = tid; idx < 1536; idx += 768) {
        int l = idx >> 9, r = idx & 511, g = r >> 7, c = r & 127;
        float v;
        if      (g == 0) v = ldin(bih, l * 384 + c, f32)       + ldin(bhh, l * 384 + c, f32);
        else if (g == 1) v = ldin(bih, l * 384 + 128 + c, f32) + ldin(bhh, l * 384 + 128 + c, f32);
        else if (g == 2) v = ldin(bih, l * 384 + 256 + c, f32);
        else             v = ldin(bhh, l * 384 + 256 + c, f32);
        biasS[idx] = v;
    }

    const int em = tid >> 2;          // embedding seq (layer-0 waves: tid<256)
    const int ej = (tid & 3) * 16;    // embedding col base
    const float peAg = ldin(peA, ((m0 + em) & 7), f32);

    __syncthreads();

#pragma unroll 1
    for (int s = 0; s < 23; s++) {
        const int l = w >> 2;           // 0..2
        const int W = w & 3;            // quarter: ctiles W*2, W*2+1
        const int t = s - 1 - l;
        if (t >= 0 && t < 20) {
            const int p = (t + 1) & 1;
            const int q = t & 1;
            const int KGI = (l == 0) ? 2 : 4;
            const _Float16* inBase = (l == 0) ? &eA[t & 1][0][0]
                                              : &hA[l - 1][t & 1][0][0];
            const int inStride = (l == 0) ? 72 : 136;

#pragma unroll
            for (int ct0 = 0; ct0 < 2; ct0++) {
                const int c8 = W * 2 + ((ct0 + ctr) & 1);   // ctile 0..7
                const int c4 = c8 * 16 + quad * 4;

                floatx4 acc[4][4];                  // [R,Z,Ni,Nh][rt] - 64 regs
#pragma unroll
                for (int g = 0; g < 4; g++) {
                    floatx4 b = *(const floatx4*)&biasS[(l * 4 + g) * 128 + c4];
#pragma unroll
                    for (int rt = 0; rt < 4; rt++) acc[g][rt] = b;
                }
                // gh: h(t-1) @ Whh^T  -- ks rotated per block, Bh per-ks
#pragma unroll
                for (int ks0 = 0; ks0 < 4; ks0++) {
                    const int ks = (ks0 + rot) & 3;
                    half8 B0 = *(const half8*)&hA[l][p][0 * 16 + nlo][ks * 32 + qk];
                    half8 B1 = *(const half8*)&hA[l][p][1 * 16 + nlo][ks * 32 + qk];
                    half8 B2 = *(const half8*)&hA[l][p][2 * 16 + nlo][ks * 32 + qk];
                    half8 B3 = *(const half8*)&hA[l][p][3 * 16 + nlo][ks * 32 + qk];
#pragma unroll
                    for (int g = 0; g < 3; g++) {
                        const int ai = (g == 2) ? 3 : g;
                        half8 Wf = *(const half8*)(ws +
                            ((long)(l * 96 + (c8 * 3 + g) * 4 + ks)) * 512 + lane * 8);
                        acc[ai][0] = MFMA16(Wf, B0, acc[ai][0]);
                        acc[ai][1] = MFMA16(Wf, B1, acc[ai][1]);
                        acc[ai][2] = MFMA16(Wf, B2, acc[ai][2]);
                        acc[ai][3] = MFMA16(Wf, B3, acc[ai][3]);
                    }
                }
                // gi: input(t) @ Wih^T  -- ks rotated, Bi per-ks
                for (int ks0 = 0; ks0 < KGI; ks0++) {
                    const int ks = (ks0 + rot) & (KGI - 1);
                    half8 B0 = *(const half8*)(inBase + (0 * 16 + nlo) * inStride + ks * 32 + qk);
                    half8 B1 = *(const half8*)(inBase + (1 * 16 + nlo) * inStride + ks * 32 + qk);
                    half8 B2 = *(const half8*)(inBase + (2 * 16 + nlo) * inStride + ks * 32 + qk);
                    half8 B3 = *(const half8*)(inBase + (3 * 16 + nlo) * inStride + ks * 32 + qk);
#pragma unroll
                    for (int g = 0; g < 3; g++) {
                        long f = (l == 0) ? (long)(480 + (c8 * 3 + g) * 2 + ks)
                                          : (long)(288 + (l - 1) * 96 + (c8 * 3 + g) * 4 + ks);
                        half8 Uf = *(const half8*)(ws + f * 512 + lane * 8);
                        acc[g][0] = MFMA16(Uf, B0, acc[g][0]);
                        acc[g][1] = MFMA16(Uf, B1, acc[g][1]);
                        acc[g][2] = MFMA16(Uf, B2, acc[g][2]);
                        acc[g][3] = MFMA16(Uf, B3, acc[g][3]);
                    }
                }
                // nonlinearity + f16 writeback (b64) to buf q
#pragma unroll
                for (int rt = 0; rt < 4; rt++) {
                    half4 ho = *(const half4*)&hA[l][p][rt * 16 + nlo][c4];
                    half4 hn;
#pragma unroll
                    for (int rg = 0; rg < 4; rg++) {
                        float r = fsigm(acc[0][rt][rg]);
                        float z = fsigm(acc[1][rt][rg]);
                        float n = ftanh(acc[2][rt][rg] + r * acc[3][rt][rg]);
                        hn[rg] = (_Float16)(n + z * ((float)ho[rg] - n));
                    }
                    *(half4*)&hA[l][q][rt * 16 + nlo][c4] = hn;
                }
            }
        }
        // ---- embedding fused into layer-0 waves: e(t=s) -> eA[s&1] ----
        if (l == 0 && s < 20) {
            float x0 = ldin(x, ((long)(m0 + em) * 20 + s) * 2 + 0, f32);
            float x1 = ldin(x, ((long)(m0 + em) * 20 + s) * 2 + 1, f32);
            float pe = ldin(peT, s, f32) + peAg;
            float xp0 = x0 + pe, xp1 = x1 + pe;
#pragma unroll
            for (int jj = 0; jj < 16; jj++) {
                float e = fmaf(emb0[ej + jj], xp0, fmaf(emb1[ej + jj], xp1, embb[ej + jj]));
                eA[s & 1][em][ej + jj] = (_Float16)fmaxf(e, 0.f);
            }
        }
        __syncthreads();   // single barrier per phase
    }

    // ---- epilogue 1: out = h3(19) @ outW^T + out_b ; h3(19) in buf 1 ----
    if (w < 8) {
        const int otile = w & 3;
        const int rtb   = (w >> 2) * 2;
        half8 Ao[4];
#pragma unroll
        for (int ks = 0; ks < 4; ks++)
            Ao[ks] = *(const half8*)(ws + ((long)(528 + otile * 4 + ks)) * 512 + lane * 8);
        floatx4 ob;
#pragma unroll
        for (int rg = 0; rg < 4; rg++) ob[rg] = ldin(outB, otile * 16 + quad * 4 + rg, f32);
#pragma unroll
        for (int rr = 0; rr < 2; rr++) {
            const int rt = rtb + rr;
            floatx4 acc = ob;
#pragma unroll
            for (int ks = 0; ks < 4; ks++) {
                half8 b = *(const half8*)&hA[2][1][rt * 16 + nlo][ks * 32 + qk];
                acc = MFMA16(Ao[ks], b, acc);
            }
            *(floatx4*)&out[(long)(m0 + rt * 16 + nlo) * 64 + otile * 16 + quad * 4] = acc;
        }
    }

    // ---- epilogue 2: hidden finals (seq % 8 == 7), h_l(19) in buf 1 ----
    for (int idx = tid; idx < 3 * 8 * 128; idx += 768) {
        int l2 = idx >> 10, r = idx & 1023, si = r >> 7, k = r & 127;
        int sq = si * 8 + 7;
        long m = m0 + sq;
        out[1048576L + ((long)l2 * 2048 + (m >> 3)) * 128 + k] =
            (float)hA[l2][1][sq][k];
    }
}

extern "C" void kernel_launch(void* const* d_in, const int* in_sizes, int n_in,
                              void* d_out, int out_size, void* d_ws, size_t ws_size,
                              hipStream_t stream)
{
    int ix = 0, ipeA = 1, ipeT = 2, iembW = 3, iembB = 4, iWih0 = 5, iWihR = 6,
        iWhh = 7, ibih = 8, ibhh = 9, ioutW = 10, ioutB = 11;
    int f64 = -1, s64 = -1, f1152 = -1, s1152 = -1;
    for (int i = 0; i < n_in; i++) {
        int s = in_sizes[i];
        if      (s == 655360) ix = i;
        else if (s == 8)      ipeA = i;
        else if (s == 20)     ipeT = i;
        else if (s == 128)    iembW = i;
        else if (s == 24576)  iWih0 = i;
        else if (s == 98304)  iWihR = i;
        else if (s == 147456) iWhh = i;
        else if (s == 8192)   ioutW = i;
        else if (s == 64)     { if (f64 < 0) f64 = i; else s64 = i; }
        else if (s == 1152)   { if (f1152 < 0) f1152 = i; else s1152 = i; }
    }
    if (f64 >= 0)   { iembB = f64;  ioutB = (s64  >= 0 ? s64  : f64); }
    if (f1152 >= 0) { ibih = f1152; ibhh = (s1152 >= 0 ? s1152 : f1152); }

    _Float16* ws = (_Float16*)d_ws;           // 544 frags * 1KB = 557056 B
    float* out = (float*)d_out;

    hipLaunchKernelGGL(prepack_kernel, dim3(544), dim3(64), 0, stream,
                       d_in[iWhh], d_in[iWihR], d_in[iWih0], d_in[ioutW],
                       d_in[ipeT], d_in[ix], ws);
    hipLaunchKernelGGL(rnn_fused, dim3(256), dim3(768), 0, stream,
                       d_in[ix], d_in[ipeA], d_in[ipeT], d_in[iembW], d_in[iembB],
                       d_in[ibih], d_in[ibhh], d_in[ioutB], ws, out);
}